// Round 7
// baseline (1058.059 us; speedup 1.0000x reference)
//
#include <hip/hip_runtime.h>
#include <math.h>

// ---------------------------------------------------------------------------
// QuantumSuperpositionAttention  (B=1, N=1024, DIM=512, H=8, DH=64, k=102)
//
// Identities:
//  * phase MLP is dead code: |alpha * e^{i phi}|^2 == |alpha|^2
//  * cayley(M): A = 0.02*((Mre - Mre^T) + i(Mim + Mim^T));
//    W = (I-A)^{-1}(I+A) = 2(I+A)X - I,  X = inv(I - A^2), spec [1,5).
//  * inv: deg-4 minimax init (PS form) + 2 quadratic NS -> rho ~ 7e-8.
//  * GEMM CORE LESSONS (R9..R18): 32x64/2x4 core at 2 waves/SIMD = ~56%
//    VALU, LDS-pipe-bound (per wave-k: 64 FMA-cyc vs ~96+ LDS-cyc x4 waves).
//    4x4 microtile halves LDS ops per FLOP but was only ever tested at
//    1 wave/SIMD (R17) or with coupled damage (R18: uncoalesced A-staging,
//    QKV swap, 8 combines). R22 = clean isolation: split-K=2, 512 blocks,
//    2 waves/SIMD, coalesced staging, raw-partial outputs (no epilogue).
//  * ERROR BUDGET (R6..R19 calibrated): floor-class (~1e-7) W realization
//    changes SAFE — R16 single-chain passed (0.01025), R18 split-K passed
//    (0.00195). 4.3e-6 residual FAILED (R19). NS chain stays 8 products.
//    Partial sums (P0+P1) and combine expressions below are BITWISE R18's.
//  * ACCURACY RULES (R7/R9): never change float summation ORDER in the
//    QKV/scores/select/gather chain. Those kernels are byte-identical here.
//  * D_OUT BOUNDS RULE (R10/R11): every d_out store bounds-checked.
//
// R22 phase-A chain (5 sk-GEMMs + 3 combines + 2 R16-GEMMs):
//   G1 sk: {S0,S1} = A*A            C0: S  = S0+S1
//   G2 sk: {T0,T1} = S*S            C2: S2 = T0+T1; U = 5.5S + 0.5S2
//   G3 R16 mode3:  X0 = (60.5I + 48S + 23S2 + S2*U)/61.5
//   G4 sk: {T0,T1} = S*X0
//   G5 sk(BM2): {P0,P1} = X0*(X0 - (T0+T1))
//   C1: Xn = 2*X0 - (P0+P1)         ... repeat G4'/G5'/C1' with Xn ...
//   G7 R16 mode4:  W = 2*Xf + 2*A*Xf - I
// ---------------------------------------------------------------------------

#define PLANE   262144      // 512*512
#define CMAT    524288      // floats per complex 512x512 (2 MB)
#define PPLANE  524288      // 1024*512
#define CPROJ   1048576     // floats per complex 1024x512 (4 MB)
#define KTOP    102

#define R_FLOATS (28*CMAT)  // 7 slots x 4 weights x CMAT
#define POOL_FLOATS (4*CMAT + 8192 + R_FLOATS)
__device__ __attribute__((aligned(256))) float g_pool[POOL_FLOATS];

// ---------------------------------------------------------------------------
// R22 split-K 4x4 core: 64x64 C-tile / 256 thr / 4x4 microtile / BK=32 /
// dbuf / split-K=2. Grid (8, 8, w*2+kh) = 512 blocks (2/CU, 2 waves/SIMD).
// Pure product partial: P[kh] = A * B over k in [kh*256, kh*256+256).
// BM=0: B = B0.   BM=2: B = B0 - (B1 + B2)   (T-reconstruct, bitwise R18).
// All matrices 512x512, per-weight stride CMAT. Raw float4 stores.
// ---------------------------------------------------------------------------
template<int BM>
__launch_bounds__(256)
__global__ void cgemm44sk_kernel(
    const float* __restrict__ Are,  const float* __restrict__ Aim,
    const float* __restrict__ B0re, const float* __restrict__ B0im,
    const float* __restrict__ B1re, const float* __restrict__ B1im,
    const float* __restrict__ B2re, const float* __restrict__ B2im,
    float* __restrict__ P0re, float* __restrict__ P0im,
    float* __restrict__ P1re, float* __restrict__ P1im)
{
    __shared__ float As_re[2][32][68], As_im[2][32][68];
    __shared__ float Bs_re[2][32][68], Bs_im[2][32][68];
    const int z = blockIdx.z, w = z >> 1, kh = z & 1;
    const int kbeg = kh << 8;            // 0 or 256
    const size_t wo = (size_t)w * CMAT;
    Are += wo; Aim += wo; B0re += wo; B0im += wo;
    float* Cre = (kh ? P1re : P0re) + wo;
    float* Cim = (kh ? P1im : P0im) + wo;
    const int tid = threadIdx.x;
    const int bm = blockIdx.y * 64, bn = blockIdx.x * 64;
    const int tm = (tid >> 4) << 2, tn = (tid & 15) << 2;
    const int lmA = tid >> 3, lkA = (tid & 7) << 2;    // rows lmA, lmA+32
    const int lkB = tid >> 4, lnB = (tid & 15) << 2;   // k-rows lkB, lkB+16
    float cr[4][4] = {{0.f}}, ci[4][4] = {{0.f}};
    const float* pAr0 = Are + (size_t)(bm + lmA) * 512 + kbeg + lkA;
    const float* pAi0 = Aim + (size_t)(bm + lmA) * 512 + kbeg + lkA;
    const float* pAr1 = pAr0 + (size_t)32 * 512;
    const float* pAi1 = pAi0 + (size_t)32 * 512;
    const size_t bo0 = (size_t)(kbeg + lkB) * 512 + bn + lnB;
    const size_t bo1 = bo0 + (size_t)16 * 512;
    // prefetch tile 0
    float4 ar0 = *(const float4*)(pAr0), ai0 = *(const float4*)(pAi0);
    float4 ar1 = *(const float4*)(pAr1), ai1 = *(const float4*)(pAi1);
    float4 b0r0 = *(const float4*)(B0re + bo0), b0i0 = *(const float4*)(B0im + bo0);
    float4 b0r1 = *(const float4*)(B0re + bo1), b0i1 = *(const float4*)(B0im + bo1);
    float4 b1r0, b1i0, b1r1, b1i1, b2r0, b2i0, b2r1, b2i1;
    if (BM == 2) {
        b1r0 = *(const float4*)(B1re + wo + bo0); b1i0 = *(const float4*)(B1im + wo + bo0);
        b1r1 = *(const float4*)(B1re + wo + bo1); b1i1 = *(const float4*)(B1im + wo + bo1);
        b2r0 = *(const float4*)(B2re + wo + bo0); b2i0 = *(const float4*)(B2im + wo + bo0);
        b2r1 = *(const float4*)(B2re + wo + bo1); b2i1 = *(const float4*)(B2im + wo + bo1);
    }
    for (int kk = 0; kk < 256; kk += 32) {
        const int buf = (kk >> 5) & 1;
        As_re[buf][lkA+0][lmA] = ar0.x; As_re[buf][lkA+1][lmA] = ar0.y;
        As_re[buf][lkA+2][lmA] = ar0.z; As_re[buf][lkA+3][lmA] = ar0.w;
        As_im[buf][lkA+0][lmA] = ai0.x; As_im[buf][lkA+1][lmA] = ai0.y;
        As_im[buf][lkA+2][lmA] = ai0.z; As_im[buf][lkA+3][lmA] = ai0.w;
        As_re[buf][lkA+0][lmA+32] = ar1.x; As_re[buf][lkA+1][lmA+32] = ar1.y;
        As_re[buf][lkA+2][lmA+32] = ar1.z; As_re[buf][lkA+3][lmA+32] = ar1.w;
        As_im[buf][lkA+0][lmA+32] = ai1.x; As_im[buf][lkA+1][lmA+32] = ai1.y;
        As_im[buf][lkA+2][lmA+32] = ai1.z; As_im[buf][lkA+3][lmA+32] = ai1.w;
        if (BM == 0) {
            *(float4*)&Bs_re[buf][lkB][lnB]    = b0r0;
            *(float4*)&Bs_im[buf][lkB][lnB]    = b0i0;
            *(float4*)&Bs_re[buf][lkB+16][lnB] = b0r1;
            *(float4*)&Bs_im[buf][lkB+16][lnB] = b0i1;
        } else {
            // b = b0 - (b1 + b2)   [bitwise R18: v=p0+p1; t = 1*D - v]
            float4 w0, w1;
            w0.x = b0r0.x - (b1r0.x + b2r0.x); w0.y = b0r0.y - (b1r0.y + b2r0.y);
            w0.z = b0r0.z - (b1r0.z + b2r0.z); w0.w = b0r0.w - (b1r0.w + b2r0.w);
            w1.x = b0r1.x - (b1r1.x + b2r1.x); w1.y = b0r1.y - (b1r1.y + b2r1.y);
            w1.z = b0r1.z - (b1r1.z + b2r1.z); w1.w = b0r1.w - (b1r1.w + b2r1.w);
            *(float4*)&Bs_re[buf][lkB][lnB]    = w0;
            *(float4*)&Bs_re[buf][lkB+16][lnB] = w1;
            w0.x = b0i0.x - (b1i0.x + b2i0.x); w0.y = b0i0.y - (b1i0.y + b2i0.y);
            w0.z = b0i0.z - (b1i0.z + b2i0.z); w0.w = b0i0.w - (b1i0.w + b2i0.w);
            w1.x = b0i1.x - (b1i1.x + b2i1.x); w1.y = b0i1.y - (b1i1.y + b2i1.y);
            w1.z = b0i1.z - (b1i1.z + b2i1.z); w1.w = b0i1.w - (b1i1.w + b2i1.w);
            *(float4*)&Bs_im[buf][lkB][lnB]    = w0;
            *(float4*)&Bs_im[buf][lkB+16][lnB] = w1;
        }
        __syncthreads();
        const int kn = kk + 32;
        if (kn < 256) {
            ar0 = *(const float4*)(pAr0 + kn); ai0 = *(const float4*)(pAi0 + kn);
            ar1 = *(const float4*)(pAr1 + kn); ai1 = *(const float4*)(pAi1 + kn);
            const size_t s = (size_t)kn * 512;
            b0r0 = *(const float4*)(B0re + bo0 + s); b0i0 = *(const float4*)(B0im + bo0 + s);
            b0r1 = *(const float4*)(B0re + bo1 + s); b0i1 = *(const float4*)(B0im + bo1 + s);
            if (BM == 2) {
                b1r0 = *(const float4*)(B1re + wo + bo0 + s); b1i0 = *(const float4*)(B1im + wo + bo0 + s);
                b1r1 = *(const float4*)(B1re + wo + bo1 + s); b1i1 = *(const float4*)(B1im + wo + bo1 + s);
                b2r0 = *(const float4*)(B2re + wo + bo0 + s); b2i0 = *(const float4*)(B2im + wo + bo0 + s);
                b2r1 = *(const float4*)(B2re + wo + bo1 + s); b2i1 = *(const float4*)(B2im + wo + bo1 + s);
            }
        }
        #pragma unroll
        for (int k = 0; k < 32; ++k) {
            const float4 xr = *(const float4*)&As_re[buf][k][tm];
            const float4 xi = *(const float4*)&As_im[buf][k][tm];
            const float4 yr = *(const float4*)&Bs_re[buf][k][tn];
            const float4 yi = *(const float4*)&Bs_im[buf][k][tn];
            const float axr[4] = {xr.x, xr.y, xr.z, xr.w};
            const float axi[4] = {xi.x, xi.y, xi.z, xi.w};
            const float byr[4] = {yr.x, yr.y, yr.z, yr.w};
            const float byi[4] = {yi.x, yi.y, yi.z, yi.w};
            #pragma unroll
            for (int i = 0; i < 4; ++i) {
                #pragma unroll
                for (int j = 0; j < 4; ++j) {
                    cr[i][j] += axr[i]*byr[j] - axi[i]*byi[j];
                    ci[i][j] += axr[i]*byi[j] + axi[i]*byr[j];
                }
            }
        }
    }
    #pragma unroll
    for (int i = 0; i < 4; ++i) {
        const size_t idx = (size_t)(bm + tm + i) * 512 + bn + tn;
        *(float4*)(Cre + idx) = make_float4(cr[i][0], cr[i][1], cr[i][2], cr[i][3]);
        *(float4*)(Cim + idx) = make_float4(ci[i][0], ci[i][1], ci[i][2], ci[i][3]);
    }
}

// ---------------------------------------------------------------------------
// Split-K combine, elementwise over CMAT floats (re+im planes linear).
// v = P0 + P1  (bitwise R18 combine order), then:
//  mode 0: O1 = v
//  mode 1: O1 = 2*D - v                (NS update; bitwise R18 mode-1)
//  mode 2: O1 = v; O2 = 5.5*D + 0.5*v  (S2 + U; bitwise R18 mode-2)
// grid (512, 4): y = weight (stride CMAT on all pointers), float4/thread.
// ---------------------------------------------------------------------------
__launch_bounds__(256)
__global__ void combine_kernel(const float* __restrict__ P0, const float* __restrict__ P1,
                               const float* __restrict__ D,
                               float* __restrict__ O1, float* __restrict__ O2, int mode)
{
    const size_t idx = (size_t)blockIdx.y * CMAT
                     + ((size_t)blockIdx.x * 256 + threadIdx.x) * 4;
    const float4 p0 = *(const float4*)(P0 + idx);
    const float4 p1 = *(const float4*)(P1 + idx);
    float v[4] = {p0.x+p1.x, p0.y+p1.y, p0.z+p1.z, p0.w+p1.w};
    if (mode == 0) {
        *(float4*)(O1 + idx) = make_float4(v[0], v[1], v[2], v[3]);
    } else if (mode == 1) {
        const float4 d = *(const float4*)(D + idx);
        *(float4*)(O1 + idx) = make_float4(2.f*d.x - v[0], 2.f*d.y - v[1],
                                           2.f*d.z - v[2], 2.f*d.w - v[3]);
    } else {
        const float4 d = *(const float4*)(D + idx);
        *(float4*)(O1 + idx) = make_float4(v[0], v[1], v[2], v[3]);
        *(float4*)(O2 + idx) = make_float4(5.5f*d.x + 0.5f*v[0], 5.5f*d.y + 0.5f*v[1],
                                           5.5f*d.z + 0.5f*v[2], 5.5f*d.w + 0.5f*v[3]);
    }
}

// ---------------------------------------------------------------------------
// Complex planar GEMM, R16 core (UNCHANGED): 32x64 / 256 thr / 2x4 / BK=32.
// Modes: 0 C=A*B; 1 C=dcoef*D-A*B; 2 S2+U; 3 X0; 4 W; 5 bounded d_out.
// ---------------------------------------------------------------------------
__launch_bounds__(256)
__global__ void cgemm_kernel(
    const float* __restrict__ Are, const float* __restrict__ Aim, int sA,
    const float* __restrict__ Bre, const float* __restrict__ Bim, int sB,
    const float* __restrict__ Dre, const float* __restrict__ Dim, int sD,
    const float* __restrict__ Ere2, float* __restrict__ Ewr, int sE,
    float* __restrict__ Cre, float* __restrict__ Cim, int sC,
    int M, int N, int Kd, float dcoef, int mode, int out_floats)
{
    __shared__ float As_re[2][32][34], As_im[2][32][34];
    __shared__ float Bs_re[2][32][68], Bs_im[2][32][68];
    const int b = blockIdx.z;
    Are += (size_t)b * sA; Aim += (size_t)b * sA;
    Bre += (size_t)b * sB; Bim += (size_t)b * sB;
    Dre += (size_t)b * sD; Dim += (size_t)b * sD;
    const float* Ere = Ere2 + (size_t)b * sE;
    const float* Eim = Ere + PLANE;
    float* Uwr = Ewr ? (Ewr + (size_t)b * sE) : (float*)0;
    Cre += (size_t)b * sC; Cim += (size_t)b * sC;
    const int bnd = mode == 5 ? (out_floats - b * sC) : 0;
    const int tid = threadIdx.x;
    const int bm = blockIdx.y * 32, bn = blockIdx.x * 64;
    const int tm = (tid >> 4) << 1;
    const int tn = (tid & 15) << 2;
    const int lmA = tid >> 3;
    const int lkA = (tid & 7) << 2;
    const int lkB = tid >> 4;
    const int lnB = (tid & 15) << 2;
    float cr[2][4] = {{0.f}}, ci[2][4] = {{0.f}};
    const float* pAre = Are + (size_t)(bm + lmA) * Kd + lkA;
    const float* pAim = Aim + (size_t)(bm + lmA) * Kd + lkA;
    const float* pBre = Bre + (size_t)lkB * N + bn + lnB;
    const float* pBim = Bim + (size_t)lkB * N + bn + lnB;
    float4 ar  = *(const float4*)(pAre);
    float4 ai  = *(const float4*)(pAim);
    float4 br0 = *(const float4*)(pBre);
    float4 bi0 = *(const float4*)(pBim);
    float4 br1 = *(const float4*)(pBre + (size_t)16 * N);
    float4 bi1 = *(const float4*)(pBim + (size_t)16 * N);
    for (int k0 = 0; k0 < Kd; k0 += 32) {
        const int buf = (k0 >> 5) & 1;
        As_re[buf][lkA+0][lmA] = ar.x; As_re[buf][lkA+1][lmA] = ar.y;
        As_re[buf][lkA+2][lmA] = ar.z; As_re[buf][lkA+3][lmA] = ar.w;
        As_im[buf][lkA+0][lmA] = ai.x; As_im[buf][lkA+1][lmA] = ai.y;
        As_im[buf][lkA+2][lmA] = ai.z; As_im[buf][lkA+3][lmA] = ai.w;
        *(float4*)&Bs_re[buf][lkB][lnB] = br0;
        *(float4*)&Bs_im[buf][lkB][lnB] = bi0;
        *(float4*)&Bs_re[buf][lkB+16][lnB] = br1;
        *(float4*)&Bs_im[buf][lkB+16][lnB] = bi1;
        __syncthreads();
        const int kn = k0 + 32;
        if (kn < Kd) {
            ar  = *(const float4*)(pAre + kn);
            ai  = *(const float4*)(pAim + kn);
            br0 = *(const float4*)(pBre + (size_t)kn * N);
            bi0 = *(const float4*)(pBim + (size_t)kn * N);
            br1 = *(const float4*)(pBre + (size_t)(kn + 16) * N);
            bi1 = *(const float4*)(pBim + (size_t)(kn + 16) * N);
        }
        #pragma unroll
        for (int k = 0; k < 32; ++k) {
            const float2 xr = *(const float2*)&As_re[buf][k][tm];
            const float2 xi = *(const float2*)&As_im[buf][k][tm];
            const float4 yr = *(const float4*)&Bs_re[buf][k][tn];
            const float4 yi = *(const float4*)&Bs_im[buf][k][tn];
            const float axr[2] = {xr.x, xr.y};
            const float axi[2] = {xi.x, xi.y};
            const float byr[4] = {yr.x, yr.y, yr.z, yr.w};
            const float byi[4] = {yi.x, yi.y, yi.z, yi.w};
            #pragma unroll
            for (int i = 0; i < 2; ++i) {
                #pragma unroll
                for (int j = 0; j < 4; ++j) {
                    cr[i][j] += axr[i]*byr[j] - axi[i]*byi[j];
                    ci[i][j] += axr[i]*byi[j] + axi[i]*byr[j];
                }
            }
        }
    }
    #pragma unroll
    for (int i = 0; i < 2; ++i) {
        const int row = bm + tm + i;
        const size_t idx = (size_t)row * N + bn + tn;
        float vr[4] = {cr[i][0], cr[i][1], cr[i][2], cr[i][3]};
        float vi[4] = {ci[i][0], ci[i][1], ci[i][2], ci[i][3]};
        if (mode == 1) {
            const float4 dr4 = *(const float4*)(Dre + idx);
            const float4 di4 = *(const float4*)(Dim + idx);
            const float dr[4] = {dr4.x, dr4.y, dr4.z, dr4.w};
            const float di[4] = {di4.x, di4.y, di4.z, di4.w};
            #pragma unroll
            for (int j = 0; j < 4; ++j) { vr[j] = dcoef*dr[j] - vr[j]; vi[j] = dcoef*di[j] - vi[j]; }
        } else if (mode == 2) {
            const float4 dr4 = *(const float4*)(Dre + idx);
            const float4 di4 = *(const float4*)(Dim + idx);
            const float dr[4] = {dr4.x, dr4.y, dr4.z, dr4.w};
            const float di[4] = {di4.x, di4.y, di4.z, di4.w};
            float ur[4], ui[4];
            #pragma unroll
            for (int j = 0; j < 4; ++j) { ur[j] = 5.5f*dr[j] + 0.5f*vr[j]; ui[j] = 5.5f*di[j] + 0.5f*vi[j]; }
            *(float4*)(Uwr + idx) = make_float4(ur[0], ur[1], ur[2], ur[3]);
            *(float4*)(Uwr + PLANE + idx) = make_float4(ui[0], ui[1], ui[2], ui[3]);
        } else if (mode == 3) {
            const float inv61 = 1.0f/61.5f;
            const float4 sr4 = *(const float4*)(Dre + idx);
            const float4 si4 = *(const float4*)(Dim + idx);
            const float4 s2r = *(const float4*)(Ere + idx);
            const float4 s2i = *(const float4*)(Eim + idx);
            const float sr[4] = {sr4.x, sr4.y, sr4.z, sr4.w};
            const float si[4] = {si4.x, si4.y, si4.z, si4.w};
            const float tr[4] = {s2r.x, s2r.y, s2r.z, s2r.w};
            const float ti[4] = {s2i.x, s2i.y, s2i.z, s2i.w};
            #pragma unroll
            for (int j = 0; j < 4; ++j) {
                const float diag = (row == bn + tn + j) ? 60.5f : 0.0f;
                vr[j] = (diag + 48.f*sr[j] + 23.f*tr[j] + vr[j]) * inv61;
                vi[j] = (       48.f*si[j] + 23.f*ti[j] + vi[j]) * inv61;
            }
        } else if (mode == 4) {
            const float4 dr4 = *(const float4*)(Dre + idx);
            const float4 di4 = *(const float4*)(Dim + idx);
            const float dr[4] = {dr4.x, dr4.y, dr4.z, dr4.w};
            const float di[4] = {di4.x, di4.y, di4.z, di4.w};
            #pragma unroll
            for (int j = 0; j < 4; ++j) {
                const float diag = (row == bn + tn + j) ? 1.0f : 0.0f;
                vr[j] = 2.f*dr[j] + 2.f*vr[j] - diag;
                vi[j] = 2.f*di[j] + 2.f*vi[j];
            }
        }
        if (mode == 5) {
            #pragma unroll
            for (int j = 0; j < 4; ++j) {
                const size_t ire = idx + j;
                const size_t iim = (size_t)PPLANE + idx + j;
                if (ire < (size_t)bnd) Cre[ire] = vr[j];
                if (iim < (size_t)bnd) Cre[iim] = vi[j];
            }
        } else {
            *(float4*)(Cre + idx) = make_float4(vr[0], vr[1], vr[2], vr[3]);
            *(float4*)(Cim + idx) = make_float4(vi[0], vi[1], vi[2], vi[3]);
        }
    }
}

// A = 0.02*((Mre - Mre^T) + i(Mim + Mim^T)); R21 LDS-transpose version.
__launch_bounds__(256)
__global__ void build_A_kernel(const float* __restrict__ W0re, const float* __restrict__ W0im,
                               const float* __restrict__ W1re, const float* __restrict__ W1im,
                               const float* __restrict__ W2re, const float* __restrict__ W2im,
                               const float* __restrict__ W3re, const float* __restrict__ W3im,
                               int aoff)
{
    __shared__ float Tre[32][33], Tim[32][33];
    float* Aout = g_pool + aoff;
    const int w = blockIdx.z;
    const float* Mre; const float* Mim;
    if      (w == 0) { Mre = W0re; Mim = W0im; }
    else if (w == 1) { Mre = W1re; Mim = W1im; }
    else if (w == 2) { Mre = W2re; Mim = W2im; }
    else             { Mre = W3re; Mim = W3im; }
    float* Are = Aout + (size_t)w * CMAT;
    float* Aim = Are + PLANE;
    const int r = blockIdx.y * 32, c = blockIdx.x * 32;
    const int tx = threadIdx.x & 31, ty = threadIdx.x >> 5;
    #pragma unroll
    for (int p = 0; p < 4; ++p) {
        const int rr = ty + 8*p;
        Tre[rr][tx] = Mre[(size_t)(c+rr)*512 + r + tx];
        Tim[rr][tx] = Mim[(size_t)(c+rr)*512 + r + tx];
    }
    __syncthreads();
    #pragma unroll
    for (int p = 0; p < 4; ++p) {
        const int rr = ty + 8*p;
        const int i = r + rr, j = c + tx;
        const size_t o = (size_t)i*512 + j;
        Are[o] = 0.02f * (Mre[o] - Tre[tx][rr]);
        Aim[o] = 0.02f * (Mim[o] + Tim[tx][rr]);
    }
}

// All heads: b2[h,n,s] = |conj(Q[n,h,:]) . K[s,h,:]|^2 * SCALE^2.  (R21)
__launch_bounds__(256)
__global__ void scores_kernel(const float* __restrict__ Qre, const float* __restrict__ Qim,
                              const float* __restrict__ Kre, const float* __restrict__ Kim,
                              float* __restrict__ B2)
{
    __shared__ float Qs_re[64][68], Qs_im[64][68], Ks_re[64][68], Ks_im[64][68];
    const int h = blockIdx.z;
    const int bm = blockIdx.y * 64, bn = blockIdx.x * 64;
    const int tid = threadIdx.x;
    const int tm = (tid >> 4) << 2, tn = (tid & 15) << 2;
    const int lm = tid >> 2;
    const int lk = (tid & 3) << 4;
    #pragma unroll
    for (int q = 0; q < 4; ++q) {
        const int kb = lk + 4*q;
        const float4 qr = *(const float4*)(Qre + (size_t)(bm+lm)*512 + h*64 + kb);
        const float4 qi = *(const float4*)(Qim + (size_t)(bm+lm)*512 + h*64 + kb);
        const float4 kr = *(const float4*)(Kre + (size_t)(bn+lm)*512 + h*64 + kb);
        const float4 ki = *(const float4*)(Kim + (size_t)(bn+lm)*512 + h*64 + kb);
        Qs_re[kb+0][lm]=qr.x; Qs_re[kb+1][lm]=qr.y; Qs_re[kb+2][lm]=qr.z; Qs_re[kb+3][lm]=qr.w;
        Qs_im[kb+0][lm]=qi.x; Qs_im[kb+1][lm]=qi.y; Qs_im[kb+2][lm]=qi.z; Qs_im[kb+3][lm]=qi.w;
        Ks_re[kb+0][lm]=kr.x; Ks_re[kb+1][lm]=kr.y; Ks_re[kb+2][lm]=kr.z; Ks_re[kb+3][lm]=kr.w;
        Ks_im[kb+0][lm]=ki.x; Ks_im[kb+1][lm]=ki.y; Ks_im[kb+2][lm]=ki.z; Ks_im[kb+3][lm]=ki.w;
    }
    __syncthreads();
    float dr[4][4] = {{0.f}}, di[4][4] = {{0.f}};
    #pragma unroll
    for (int k = 0; k < 64; ++k) {
        const float4 xr = *(const float4*)&Qs_re[k][tm];
        const float4 xi = *(const float4*)&Qs_im[k][tm];
        const float4 yr = *(const float4*)&Ks_re[k][tn];
        const float4 yi = *(const float4*)&Ks_im[k][tn];
        const float axr[4] = {xr.x, xr.y, xr.z, xr.w};
        const float axi[4] = {xi.x, xi.y, xi.z, xi.w};
        const float byr[4] = {yr.x, yr.y, yr.z, yr.w};
        const float byi[4] = {yi.x, yi.y, yi.z, yi.w};
        #pragma unroll
        for (int i = 0; i < 4; ++i) {
            #pragma unroll
            for (int j = 0; j < 4; ++j) {
                dr[i][j] += axr[i]*byr[j] + axi[i]*byi[j];
                di[i][j] += axr[i]*byi[j] - axi[i]*byr[j];
            }
        }
    }
    #pragma unroll
    for (int i = 0; i < 4; ++i) {
        #pragma unroll
        for (int j = 0; j < 4; ++j) {
            const float b2v = (dr[i][j]*dr[i][j] + di[i][j]*di[i][j]) * 0.015625f;
            B2[(size_t)h*1048576 + (size_t)(bm+tm+i)*1024 + (bn+tn+j)] = b2v;
        }
    }
}

// Per (h,n) row: exact top-102 radix select, softmax, weighted V gather. (R21)
__launch_bounds__(256)
__global__ void select_kernel(const float* __restrict__ B2,
                              const float* __restrict__ Vre, const float* __restrict__ Vim,
                              float* __restrict__ AOre, float* __restrict__ AOim)
{
    __shared__ float sv[1024];
    __shared__ unsigned int hist[256];
    __shared__ int ssum[256];
    __shared__ int wtot[4];
    __shared__ unsigned int sc[4];
    __shared__ float sel_v[104];
    __shared__ int sel_i[104];
    __shared__ float sel_w[104];
    __shared__ float rbuf[256];
    __shared__ float srow_sh;
    const int bid = blockIdx.x;
    const int h = bid >> 10, n = bid & 1023;
    const int tid = threadIdx.x;
    const float* row = B2 + (size_t)h * 1048576 + (size_t)n * 1024;
    #pragma unroll
    for (int e = 0; e < 4; ++e) sv[tid + 256*e] = row[tid + 256*e];
    if (tid == 0) sc[2] = 0u;
    __syncthreads();

    rbuf[tid] = sv[tid] + sv[tid+256] + sv[tid+512] + sv[tid+768];
    __syncthreads();
    for (int st = 128; st > 0; st >>= 1) { if (tid < st) rbuf[tid] += rbuf[tid + st]; __syncthreads(); }
    if (tid == 0) srow_sh = rbuf[0];
    __syncthreads();

    const int lane = tid & 63, wv = tid >> 6;
    unsigned prefix = 0u, pmask = 0u;
    int krem = KTOP;
    for (int pass = 0; pass < 4; ++pass) {
        const int shift = 24 - 8 * pass;
        hist[tid] = 0u;
        __syncthreads();
        #pragma unroll
        for (int e = 0; e < 4; ++e) {
            const unsigned u = __float_as_uint(sv[tid + 256*e]);
            if ((u & pmask) == prefix) atomicAdd(&hist[(u >> shift) & 255u], 1u);
        }
        __syncthreads();
        int v = (int)hist[tid];
        #pragma unroll
        for (int off = 1; off < 64; off <<= 1) {
            const int o = __shfl_down(v, off);
            if (lane + off < 64) v += o;
        }
        if (lane == 0) wtot[wv] = v;
        __syncthreads();
        int addv = 0;
        for (int w2 = wv + 1; w2 < 4; ++w2) addv += wtot[w2];
        ssum[tid] = v + addv;
        __syncthreads();
        const int above = (tid < 255) ? ssum[tid + 1] : 0;
        if (ssum[tid] >= krem && above < krem) {
            sc[0] = (unsigned)tid;
            sc[1] = (unsigned)(krem - above);
        }
        __syncthreads();
        prefix |= sc[0] << shift;
        pmask |= 0xFFu << shift;
        krem = (int)sc[1];
        __syncthreads();
    }
    const unsigned T = prefix;
    const int m = krem;

    #pragma unroll
    for (int e = 0; e < 4; ++e) {
        const int i = tid + 256*e;
        const float v = sv[i];
        const unsigned u = __float_as_uint(v);
        bool sel = (u > T);
        if (!sel && u == T) {
            int rank = 0;
            for (int j = 0; j < i; ++j) rank += (__float_as_uint(sv[j]) == T) ? 1 : 0;
            sel = (rank < m);
        }
        if (sel) {
            const unsigned p = atomicAdd(&sc[2], 1u);
            if (p < 104u) { sel_v[p] = v; sel_i[p] = i; }
        }
    }
    __syncthreads();

    rbuf[tid] = (tid < KTOP) ? sel_v[tid] : 0.f;
    __syncthreads();
    for (int st = 128; st > 0; st >>= 1) { if (tid < st) rbuf[tid] += rbuf[tid + st]; __syncthreads(); }
    const float sumtop = rbuf[0];
    __syncthreads();
    rbuf[tid] = (tid < KTOP) ? sel_v[tid] : -1.f;
    __syncthreads();
    for (int st = 128; st > 0; st >>= 1) { if (tid < st) rbuf[tid] = fmaxf(rbuf[tid], rbuf[tid + st]); __syncthreads(); }
    const float vmax = rbuf[0];
    __syncthreads();

    const float denom = sumtop + 1e-8f * srow_sh;
    const float scl = (float)KTOP / denom;
    if (tid < KTOP) sel_w[tid] = expf(sel_v[tid] * scl - vmax * scl);
    __syncthreads();
    rbuf[tid] = (tid < KTOP) ? sel_w[tid] : 0.f;
    __syncthreads();
    for (int st = 128; st > 0; st >>= 1) { if (tid < st) rbuf[tid] += rbuf[tid + st]; __syncthreads(); }
    const float Z = rbuf[0];
    __syncthreads();

    if (tid < 128) {
        const int d = tid & 63;
        const int im = tid >> 6;
        const float* Vp = im ? Vim : Vre;
        const int base = h * 64 + d;
        float acc = 0.f;
        for (int j = 0; j < KTOP; ++j) acc += sel_w[j] * Vp[(size_t)sel_i[j] * 512 + base];
        acc /= Z;
        float* AOp = im ? AOim : AOre;
        AOp[(size_t)n * 512 + h * 64 + d] = acc;
    }
}

// ---------------------------------------------------------------------------
extern "C" void kernel_launch(void* const* d_in, const int* in_sizes, int n_in,
                              void* d_out, int out_size, void* d_ws, size_t ws_size,
                              hipStream_t stream)
{
    (void)in_sizes; (void)n_in; (void)d_ws; (void)ws_size;
    const float* x_re = (const float*)d_in[0];
    const float* x_im = (const float*)d_in[1];

    float* pool = nullptr;
    hipGetSymbolAddress((void**)&pool, HIP_SYMBOL(g_pool));   // query only; capture-safe

    float* Wall = pool;
    float* R    = Wall + 4*CMAT + 8192;
    // Phase-A slots (4 weights x CMAT each):
    float* s0 = R;              // A
    float* s1 = R + 4*CMAT;     // S0 -> S
    float* s2 = R + 8*CMAT;     // S1 -> S2h0 -> S2 -> P0 -> Xn
    float* s3 = R + 12*CMAT;    // S2h1 -> U -> P1 -> P'0 -> Xf
    float* s4 = R + 16*CMAT;    // X0 -> P'1
    float* s5 = R + 20*CMAT;    // T0 / T'0
    float* s6 = R + 24*CMAT;    // T1 / T'1
    // Phase B overlay:
    float* Q  = R;
    float* Kp = R + CPROJ;
    float* V  = R + 2*CPROJ;
    float* AO = R + 3*CPROJ;
    float* B2 = R + 4*CPROJ;    // 16 CMAT, ends at 24 CMAT

    const int aoff = (int)(s0 - pool);
    const dim3 gSK(8, 8, 8);    // 512 blocks: z = w*2 + khalf
    const dim3 gCB(512, 4);
    const dim3 gG(8, 16, 4);

    // ---- Phase A ----
    build_A_kernel<<<dim3(16,16,4),256,0,stream>>>(
        (const float*)d_in[2],(const float*)d_in[3],(const float*)d_in[4],(const float*)d_in[5],
        (const float*)d_in[6],(const float*)d_in[7],(const float*)d_in[8],(const float*)d_in[9], aoff);
    // G1: {s1,s2} = A*A halves; C: S = s1+s2 -> s1 (in-place, elementwise)
    cgemm44sk_kernel<0><<<gSK,256,0,stream>>>(s0,s0+PLANE, s0,s0+PLANE,
                                              nullptr,nullptr, nullptr,nullptr,
                                              s1,s1+PLANE, s2,s2+PLANE);
    combine_kernel<<<gCB,256,0,stream>>>(s1, s2, nullptr, s1, nullptr, 0);
    // G2: {s2,s3} = S*S halves; C: S2 = s2+s3 -> s2; U = 5.5S+0.5S2 -> s3
    cgemm44sk_kernel<0><<<gSK,256,0,stream>>>(s1,s1+PLANE, s1,s1+PLANE,
                                              nullptr,nullptr, nullptr,nullptr,
                                              s2,s2+PLANE, s3,s3+PLANE);
    combine_kernel<<<gCB,256,0,stream>>>(s2, s3, s1, s2, s3, 2);
    // G3: X0 = (60.5I + 48S + 23S2 + S2*U)/61.5 -> s4  (R16 core, mode 3)
    cgemm_kernel<<<gG,256,0,stream>>>(s2,s2+PLANE,CMAT, s3,s3+PLANE,CMAT,
                                      s1,s1+PLANE,CMAT, s2,nullptr,CMAT,
                                      s4,s4+PLANE,CMAT, 512,512,512, 0.f, 3, 0);
    // NS iteration 1: T halves = S*X0; P halves = X0*(X0-(T0+T1)); Xn = 2X0-(P0+P1)
    cgemm44sk_kernel<0><<<gSK,256,0,stream>>>(s1,s1+PLANE, s4,s4+PLANE,
                                              nullptr,nullptr, nullptr,nullptr,
                                              s5,s5+PLANE, s6,s6+PLANE);
    cgemm44sk_kernel<2><<<gSK,256,0,stream>>>(s4,s4+PLANE, s4,s4+PLANE,
                                              s5,s5+PLANE, s6,s6+PLANE,
                                              s2,s2+PLANE, s3,s3+PLANE);
    combine_kernel<<<gCB,256,0,stream>>>(s2, s3, s4, s2, nullptr, 1);   // Xn -> s2
    // NS iteration 2: T' = S*Xn -> {s5,s6}; P' = Xn*(Xn-(T'0+T'1)) -> {s3,s4}
    cgemm44sk_kernel<0><<<gSK,256,0,stream>>>(s1,s1+PLANE, s2,s2+PLANE,
                                              nullptr,nullptr, nullptr,nullptr,
                                              s5,s5+PLANE, s6,s6+PLANE);
    cgemm44sk_kernel<2><<<gSK,256,0,stream>>>(s2,s2+PLANE, s2,s2+PLANE,
                                              s5,s5+PLANE, s6,s6+PLANE,
                                              s3,s3+PLANE, s4,s4+PLANE);
    combine_kernel<<<gCB,256,0,stream>>>(s3, s4, s2, s3, nullptr, 1);   // Xf -> s3
    // G7: W = 2*Xf + 2*A*Xf - I -> Wall  (R16 core, mode 4)
    cgemm_kernel<<<gG,256,0,stream>>>(s0,s0+PLANE,CMAT, s3,s3+PLANE,CMAT,
                                      s3,s3+PLANE,CMAT, s1,nullptr,CMAT,
                                      Wall,Wall+PLANE,CMAT, 512,512,512, 0.f, 4, 0);

    // ---- Phase B: projections Q,K,V = x @ W[0..2] (R16 core, mode 0) ----
    cgemm_kernel<<<dim3(8,32,3),256,0,stream>>>(x_re,x_im,0, Wall,Wall+PLANE,CMAT,
                                                x_re,x_im,0, s1,nullptr,0,
                                                Q,Q+PPLANE,CPROJ, 1024,512,512, 0.f, 0, 0);

    scores_kernel<<<dim3(16,16,8),256,0,stream>>>(Q,Q+PPLANE, Kp,Kp+PPLANE, B2);
    select_kernel<<<8192,256,0,stream>>>(B2, V,V+PPLANE, AO,AO+PPLANE);

    // ---- Output projection straight to d_out (mode 5: bounded scalar) ----
    cgemm_kernel<<<dim3(8,16,2),256,0,stream>>>(AO,AO+PPLANE,PLANE, Wall+3*CMAT,Wall+3*CMAT+PLANE,0,
                                                AO,AO+PPLANE,0, s1,nullptr,0,
                                                (float*)d_out,nullptr,PLANE, 512,512,512, 0.f, 5, out_size);
}

// Round 8
// 1009.362 us; speedup vs baseline: 1.0482x; 1.0482x over previous
//
#include <hip/hip_runtime.h>
#include <math.h>

// ---------------------------------------------------------------------------
// QuantumSuperpositionAttention  (B=1, N=1024, DIM=512, H=8, DH=64, k=102)
//
// Identities:
//  * phase MLP is dead code: |alpha * e^{i phi}|^2 == |alpha|^2
//  * cayley(M): A = 0.02*((Mre - Mre^T) + i(Mim + Mim^T));
//    W = (I-A)^{-1}(I+A) = 2(I+A)X - I,  X = inv(I - A^2), spec [1,5).
//  * inv: deg-4 minimax init (PS form) + 2 quadratic NS -> rho ~ 7e-8.
//  * GEMM CORE — PLATEAU ESTABLISHED (R9..R22, 7 configs): 2x4@2blk,
//    4x4@1blk (R17), 4x4-128thr@3blk (R18), split-K 4x4@2blk coalesced
//    (R22), +-dbuf, +-split-K ALL converge at ~52 TF effective (33% of
//    fp32 peak), VALUBusy ~56%. R22 refuted the LDS-ratio theory clean:
//    0.375 vs 0.25 LDS-floats/FMA at equal occupancy = identical time.
//    scores_kernel (stage-once, straight-line, no K-loop) hits 2x the
//    rate at the SAME occupancy => the wall is the K-loop stage/barrier
//    cadence, irreducible for K=512 (strips exceed LDS). CLOSED.
//  * ALGORITHMIC FLOOR: 8-product chain is PS-minimal; cubic NS FAILED
//    accuracy (R19); MFMA bf16-split priced out (N~1024 -> ~90TF before
//    the >=6x split multiplier). CLOSED.
//  * ERROR BUDGET (calibrated): floor-class (~1e-7) W realization changes
//    SAFE (R18/R22 passed, absmax 0.00195). 4.3e-6 FAILED (R19). Baseline
//    absmax 0.01025 = 94% of threshold: top-k ties have NO slack.
//  * ACCURACY RULES (R7/R9): never change float summation ORDER anywhere
//    in Wq/Wk/Q/K/scores/select-weights/gather. Integer restructures are
//    bit-exact and free.
//  * denom = sumtop + 1e-8*S_row: S_row order-insensitive (sub-ulp; the
//    historical float-atomic RS passed with stable absmax).
//  * select kernel is near its V-gather traffic floor (~428 MB gathers).
//  * D_OUT BOUNDS RULE (R10/R11): every d_out store bounds-checked.
//
// R23 = R21 verbatim (995.9us PASS, absmax 0.01025391 — session best).
// ---------------------------------------------------------------------------

#define PLANE   262144      // 512*512
#define CMAT    524288      // floats per complex 512x512 (2 MB)
#define PPLANE  524288      // 1024*512
#define CPROJ   1048576     // floats per complex 1024x512 (4 MB)
#define KTOP    102

#define R_FLOATS 12582912
#define POOL_FLOATS (4*CMAT + 8192 + R_FLOATS)
__device__ __attribute__((aligned(256))) float g_pool[POOL_FLOATS];

// ---------------------------------------------------------------------------
// Complex planar GEMM, R16 core: 32x64 C-tile / 256 thr / 2x4 microtile /
// BK=32 / LDS double-buffer + reg prefetch. Grid (N/64, M/32, batch).
// Epilogue modes:
//  0: C = A*B
//  1: C = dcoef*D - A*B                       (NS steps)
//  2: C = A*B (=S2);  E = 5.5*D + 0.5*C      (D=S, E=U)
//  3: C = (60.5*I + 48*D + 23*E + A*B)/61.5  (D=S, E=S2; C=X0)
//  4: C = 2*D + 2*A*B - I                    (D=X; C=W)
//  5: C = A*B, scalar stores bounded by out_floats; im plane at +PPLANE
//     (bnd = out_floats - b*sC; global im index = b*sC + PPLANE + idx)
// ---------------------------------------------------------------------------
__launch_bounds__(256)
__global__ void cgemm_kernel(
    const float* __restrict__ Are, const float* __restrict__ Aim, int sA,
    const float* __restrict__ Bre, const float* __restrict__ Bim, int sB,
    const float* __restrict__ Dre, const float* __restrict__ Dim, int sD,
    const float* __restrict__ Ere2, float* __restrict__ Ewr, int sE,
    float* __restrict__ Cre, float* __restrict__ Cim, int sC,
    int M, int N, int Kd, float dcoef, int mode, int out_floats)
{
    __shared__ float As_re[2][32][34], As_im[2][32][34];
    __shared__ float Bs_re[2][32][68], Bs_im[2][32][68];
    const int b = blockIdx.z;
    Are += (size_t)b * sA; Aim += (size_t)b * sA;
    Bre += (size_t)b * sB; Bim += (size_t)b * sB;
    Dre += (size_t)b * sD; Dim += (size_t)b * sD;
    const float* Ere = Ere2 + (size_t)b * sE;
    const float* Eim = Ere + PLANE;      // E input (S2) planes
    float* Uwr = Ewr ? (Ewr + (size_t)b * sE) : (float*)0;
    Cre += (size_t)b * sC; Cim += (size_t)b * sC;
    const int bnd = mode == 5 ? (out_floats - b * sC) : 0;
    const int tid = threadIdx.x;
    const int bm = blockIdx.y * 32, bn = blockIdx.x * 64;
    const int tm = (tid >> 4) << 1;      // 0..30 (2 rows)
    const int tn = (tid & 15) << 2;      // 0..60 (4 cols)
    const int lmA = tid >> 3;            // 0..31
    const int lkA = (tid & 7) << 2;      // 0,4..28
    const int lkB = tid >> 4;            // 0..15
    const int lnB = (tid & 15) << 2;     // 0..60
    float cr[2][4] = {{0.f}}, ci[2][4] = {{0.f}};
    const float* pAre = Are + (size_t)(bm + lmA) * Kd + lkA;
    const float* pAim = Aim + (size_t)(bm + lmA) * Kd + lkA;
    const float* pBre = Bre + (size_t)lkB * N + bn + lnB;
    const float* pBim = Bim + (size_t)lkB * N + bn + lnB;
    // preload K-tile 0 into registers
    float4 ar  = *(const float4*)(pAre);
    float4 ai  = *(const float4*)(pAim);
    float4 br0 = *(const float4*)(pBre);
    float4 bi0 = *(const float4*)(pBim);
    float4 br1 = *(const float4*)(pBre + (size_t)16 * N);
    float4 bi1 = *(const float4*)(pBim + (size_t)16 * N);
    for (int k0 = 0; k0 < Kd; k0 += 32) {
        const int buf = (k0 >> 5) & 1;
        As_re[buf][lkA+0][lmA] = ar.x; As_re[buf][lkA+1][lmA] = ar.y;
        As_re[buf][lkA+2][lmA] = ar.z; As_re[buf][lkA+3][lmA] = ar.w;
        As_im[buf][lkA+0][lmA] = ai.x; As_im[buf][lkA+1][lmA] = ai.y;
        As_im[buf][lkA+2][lmA] = ai.z; As_im[buf][lkA+3][lmA] = ai.w;
        *(float4*)&Bs_re[buf][lkB][lnB] = br0;
        *(float4*)&Bs_im[buf][lkB][lnB] = bi0;
        *(float4*)&Bs_re[buf][lkB+16][lnB] = br1;
        *(float4*)&Bs_im[buf][lkB+16][lnB] = bi1;
        __syncthreads();
        // issue next tile's global loads; latency hides under compute below
        const int kn = k0 + 32;
        if (kn < Kd) {
            ar  = *(const float4*)(pAre + kn);
            ai  = *(const float4*)(pAim + kn);
            br0 = *(const float4*)(pBre + (size_t)kn * N);
            bi0 = *(const float4*)(pBim + (size_t)kn * N);
            br1 = *(const float4*)(pBre + (size_t)(kn + 16) * N);
            bi1 = *(const float4*)(pBim + (size_t)(kn + 16) * N);
        }
        #pragma unroll
        for (int k = 0; k < 32; ++k) {
            const float2 xr = *(const float2*)&As_re[buf][k][tm];
            const float2 xi = *(const float2*)&As_im[buf][k][tm];
            const float4 yr = *(const float4*)&Bs_re[buf][k][tn];
            const float4 yi = *(const float4*)&Bs_im[buf][k][tn];
            const float axr[2] = {xr.x, xr.y};
            const float axi[2] = {xi.x, xi.y};
            const float byr[4] = {yr.x, yr.y, yr.z, yr.w};
            const float byi[4] = {yi.x, yi.y, yi.z, yi.w};
            #pragma unroll
            for (int i = 0; i < 2; ++i) {
                #pragma unroll
                for (int j = 0; j < 4; ++j) {
                    cr[i][j] += axr[i]*byr[j] - axi[i]*byi[j];
                    ci[i][j] += axr[i]*byi[j] + axi[i]*byr[j];
                }
            }
        }
    }
    #pragma unroll
    for (int i = 0; i < 2; ++i) {
        const int row = bm + tm + i;
        const size_t idx = (size_t)row * N + bn + tn;
        float vr[4] = {cr[i][0], cr[i][1], cr[i][2], cr[i][3]};
        float vi[4] = {ci[i][0], ci[i][1], ci[i][2], ci[i][3]};
        if (mode == 1) {
            const float4 dr4 = *(const float4*)(Dre + idx);
            const float4 di4 = *(const float4*)(Dim + idx);
            const float dr[4] = {dr4.x, dr4.y, dr4.z, dr4.w};
            const float di[4] = {di4.x, di4.y, di4.z, di4.w};
            #pragma unroll
            for (int j = 0; j < 4; ++j) { vr[j] = dcoef*dr[j] - vr[j]; vi[j] = dcoef*di[j] - vi[j]; }
        } else if (mode == 2) {
            const float4 dr4 = *(const float4*)(Dre + idx);
            const float4 di4 = *(const float4*)(Dim + idx);
            const float dr[4] = {dr4.x, dr4.y, dr4.z, dr4.w};
            const float di[4] = {di4.x, di4.y, di4.z, di4.w};
            float ur[4], ui[4];
            #pragma unroll
            for (int j = 0; j < 4; ++j) { ur[j] = 5.5f*dr[j] + 0.5f*vr[j]; ui[j] = 5.5f*di[j] + 0.5f*vi[j]; }
            *(float4*)(Uwr + idx) = make_float4(ur[0], ur[1], ur[2], ur[3]);
            *(float4*)(Uwr + PLANE + idx) = make_float4(ui[0], ui[1], ui[2], ui[3]);
        } else if (mode == 3) {
            const float inv61 = 1.0f/61.5f;
            const float4 sr4 = *(const float4*)(Dre + idx);
            const float4 si4 = *(const float4*)(Dim + idx);
            const float4 s2r = *(const float4*)(Ere + idx);
            const float4 s2i = *(const float4*)(Eim + idx);
            const float sr[4] = {sr4.x, sr4.y, sr4.z, sr4.w};
            const float si[4] = {si4.x, si4.y, si4.z, si4.w};
            const float tr[4] = {s2r.x, s2r.y, s2r.z, s2r.w};
            const float ti[4] = {s2i.x, s2i.y, s2i.z, s2i.w};
            #pragma unroll
            for (int j = 0; j < 4; ++j) {
                const float diag = (row == bn + tn + j) ? 60.5f : 0.0f;
                vr[j] = (diag + 48.f*sr[j] + 23.f*tr[j] + vr[j]) * inv61;
                vi[j] = (       48.f*si[j] + 23.f*ti[j] + vi[j]) * inv61;
            }
        } else if (mode == 4) {
            const float4 dr4 = *(const float4*)(Dre + idx);
            const float4 di4 = *(const float4*)(Dim + idx);
            const float dr[4] = {dr4.x, dr4.y, dr4.z, dr4.w};
            const float di[4] = {di4.x, di4.y, di4.z, di4.w};
            #pragma unroll
            for (int j = 0; j < 4; ++j) {
                const float diag = (row == bn + tn + j) ? 1.0f : 0.0f;
                vr[j] = 2.f*dr[j] + 2.f*vr[j] - diag;
                vi[j] = 2.f*di[j] + 2.f*vi[j];
            }
        }
        if (mode == 5) {
            // bounded scalar stores straight to d_out (copy_out semantics)
            #pragma unroll
            for (int j = 0; j < 4; ++j) {
                const size_t ire = idx + j;
                const size_t iim = (size_t)PPLANE + idx + j;
                if (ire < (size_t)bnd) Cre[ire] = vr[j];
                if (iim < (size_t)bnd) Cre[iim] = vi[j];
            }
        } else {
            *(float4*)(Cre + idx) = make_float4(vr[0], vr[1], vr[2], vr[3]);
            *(float4*)(Cim + idx) = make_float4(vi[0], vi[1], vi[2], vi[3]);
        }
    }
}

// A = 0.02*((Mre - Mre^T) + i(Mim + Mim^T)) for all 4 weights.
// R21: 32x32 LDS-transpose tiles; both M reads coalesced. Same arithmetic.
// grid (16, 16, 4), 256 threads.
__launch_bounds__(256)
__global__ void build_A_kernel(const float* __restrict__ W0re, const float* __restrict__ W0im,
                               const float* __restrict__ W1re, const float* __restrict__ W1im,
                               const float* __restrict__ W2re, const float* __restrict__ W2im,
                               const float* __restrict__ W3re, const float* __restrict__ W3im,
                               int aoff)
{
    __shared__ float Tre[32][33], Tim[32][33];
    float* Aout = g_pool + aoff;
    const int w = blockIdx.z;
    const float* Mre; const float* Mim;
    if      (w == 0) { Mre = W0re; Mim = W0im; }
    else if (w == 1) { Mre = W1re; Mim = W1im; }
    else if (w == 2) { Mre = W2re; Mim = W2im; }
    else             { Mre = W3re; Mim = W3im; }
    float* Are = Aout + (size_t)w * CMAT;
    float* Aim = Are + PLANE;
    const int r = blockIdx.y * 32, c = blockIdx.x * 32;
    const int tx = threadIdx.x & 31, ty = threadIdx.x >> 5;   // 8 rows/pass
    // stage M tile (c..c+31 rows, r..r+31 cols) for the transpose term
    #pragma unroll
    for (int p = 0; p < 4; ++p) {
        const int rr = ty + 8*p;
        Tre[rr][tx] = Mre[(size_t)(c+rr)*512 + r + tx];
        Tim[rr][tx] = Mim[(size_t)(c+rr)*512 + r + tx];
    }
    __syncthreads();
    #pragma unroll
    for (int p = 0; p < 4; ++p) {
        const int rr = ty + 8*p;            // local row in A tile
        const int i = r + rr, j = c + tx;   // global (i,j)
        const size_t o = (size_t)i*512 + j;
        Are[o] = 0.02f * (Mre[o] - Tre[tx][rr]);   // Mre[j][i]
        Aim[o] = 0.02f * (Mim[o] + Tim[tx][rr]);   // Mim[j][i]
    }
}

// All heads: b2[h,n,s] = |conj(Q[n,h,:]) . K[s,h,:]|^2 * SCALE^2.
// R20 full-K staging; R21: RS/atomic tail removed (select computes S_row).
__launch_bounds__(256)
__global__ void scores_kernel(const float* __restrict__ Qre, const float* __restrict__ Qim,
                              const float* __restrict__ Kre, const float* __restrict__ Kim,
                              float* __restrict__ B2)
{
    __shared__ float Qs_re[64][68], Qs_im[64][68], Ks_re[64][68], Ks_im[64][68];
    const int h = blockIdx.z;
    const int bm = blockIdx.y * 64, bn = blockIdx.x * 64;
    const int tid = threadIdx.x;
    const int tm = (tid >> 4) << 2, tn = (tid & 15) << 2;
    const int lm = tid >> 2;            // 0..63 (tile row)
    const int lk = (tid & 3) << 4;      // 0,16,32,48 (k-chunk base)
    #pragma unroll
    for (int q = 0; q < 4; ++q) {
        const int kb = lk + 4*q;
        const float4 qr = *(const float4*)(Qre + (size_t)(bm+lm)*512 + h*64 + kb);
        const float4 qi = *(const float4*)(Qim + (size_t)(bm+lm)*512 + h*64 + kb);
        const float4 kr = *(const float4*)(Kre + (size_t)(bn+lm)*512 + h*64 + kb);
        const float4 ki = *(const float4*)(Kim + (size_t)(bn+lm)*512 + h*64 + kb);
        Qs_re[kb+0][lm]=qr.x; Qs_re[kb+1][lm]=qr.y; Qs_re[kb+2][lm]=qr.z; Qs_re[kb+3][lm]=qr.w;
        Qs_im[kb+0][lm]=qi.x; Qs_im[kb+1][lm]=qi.y; Qs_im[kb+2][lm]=qi.z; Qs_im[kb+3][lm]=qi.w;
        Ks_re[kb+0][lm]=kr.x; Ks_re[kb+1][lm]=kr.y; Ks_re[kb+2][lm]=kr.z; Ks_re[kb+3][lm]=kr.w;
        Ks_im[kb+0][lm]=ki.x; Ks_im[kb+1][lm]=ki.y; Ks_im[kb+2][lm]=ki.z; Ks_im[kb+3][lm]=ki.w;
    }
    __syncthreads();
    float dr[4][4] = {{0.f}}, di[4][4] = {{0.f}};
    #pragma unroll
    for (int k = 0; k < 64; ++k) {
        const float4 xr = *(const float4*)&Qs_re[k][tm];
        const float4 xi = *(const float4*)&Qs_im[k][tm];
        const float4 yr = *(const float4*)&Ks_re[k][tn];
        const float4 yi = *(const float4*)&Ks_im[k][tn];
        const float axr[4] = {xr.x, xr.y, xr.z, xr.w};
        const float axi[4] = {xi.x, xi.y, xi.z, xi.w};
        const float byr[4] = {yr.x, yr.y, yr.z, yr.w};
        const float byi[4] = {yi.x, yi.y, yi.z, yi.w};
        #pragma unroll
        for (int i = 0; i < 4; ++i) {
            #pragma unroll
            for (int j = 0; j < 4; ++j) {
                dr[i][j] += axr[i]*byr[j] + axi[i]*byi[j];   // re(conj(q)*k)
                di[i][j] += axr[i]*byi[j] - axi[i]*byr[j];   // im(conj(q)*k)
            }
        }
    }
    #pragma unroll
    for (int i = 0; i < 4; ++i) {
        #pragma unroll
        for (int j = 0; j < 4; ++j) {
            const float b2v = (dr[i][j]*dr[i][j] + di[i][j]*di[i][j]) * 0.015625f;
            B2[(size_t)h*1048576 + (size_t)(bm+tm+i)*1024 + (bn+tn+j)] = b2v;
        }
    }
}

// Per (h,n) row: exact top-102 radix select, softmax, weighted V gather.
// R21: shfl-based integer suffix scan; in-block S_row (1e-8-scaled term).
__launch_bounds__(256)
__global__ void select_kernel(const float* __restrict__ B2,
                              const float* __restrict__ Vre, const float* __restrict__ Vim,
                              float* __restrict__ AOre, float* __restrict__ AOim)
{
    __shared__ float sv[1024];
    __shared__ unsigned int hist[256];
    __shared__ int ssum[256];
    __shared__ int wtot[4];
    __shared__ unsigned int sc[4];
    __shared__ float sel_v[104];
    __shared__ int sel_i[104];
    __shared__ float sel_w[104];
    __shared__ float rbuf[256];
    __shared__ float srow_sh;
    const int bid = blockIdx.x;
    const int h = bid >> 10, n = bid & 1023;
    const int tid = threadIdx.x;
    const float* row = B2 + (size_t)h * 1048576 + (size_t)n * 1024;
    #pragma unroll
    for (int e = 0; e < 4; ++e) sv[tid + 256*e] = row[tid + 256*e];
    if (tid == 0) sc[2] = 0u;
    __syncthreads();

    // S_row = sum of the full row (deterministic tree). Enters denom only
    // as 1e-8*S_row (sub-ulp of denom) -> order-insensitive, proven by the
    // historical float-atomic RS passing with stable absmax.
    rbuf[tid] = sv[tid] + sv[tid+256] + sv[tid+512] + sv[tid+768];
    __syncthreads();
    for (int st = 128; st > 0; st >>= 1) { if (tid < st) rbuf[tid] += rbuf[tid + st]; __syncthreads(); }
    if (tid == 0) srow_sh = rbuf[0];
    __syncthreads();

    const int lane = tid & 63, wv = tid >> 6;
    unsigned prefix = 0u, pmask = 0u;
    int krem = KTOP;
    for (int pass = 0; pass < 4; ++pass) {
        const int shift = 24 - 8 * pass;
        hist[tid] = 0u;
        __syncthreads();
        #pragma unroll
        for (int e = 0; e < 4; ++e) {
            const unsigned u = __float_as_uint(sv[tid + 256*e]);
            if ((u & pmask) == prefix) atomicAdd(&hist[(u >> shift) & 255u], 1u);
        }
        __syncthreads();
        // integer suffix scan: ssum[t] = sum_{t'>=t} hist[t'] (bit-exact)
        int v = (int)hist[tid];
        #pragma unroll
        for (int off = 1; off < 64; off <<= 1) {
            const int o = __shfl_down(v, off);
            if (lane + off < 64) v += o;
        }
        if (lane == 0) wtot[wv] = v;           // wave totals (lane 0 = full)
        __syncthreads();
        int addv = 0;
        for (int w2 = wv + 1; w2 < 4; ++w2) addv += wtot[w2];
        ssum[tid] = v + addv;
        __syncthreads();
        const int above = (tid < 255) ? ssum[tid + 1] : 0;
        if (ssum[tid] >= krem && above < krem) {
            sc[0] = (unsigned)tid;
            sc[1] = (unsigned)(krem - above);
        }
        __syncthreads();
        prefix |= sc[0] << shift;
        pmask |= 0xFFu << shift;
        krem = (int)sc[1];
        __syncthreads();
    }
    const unsigned T = prefix;
    const int m = krem;   // ties at T: lowest indices first (jax top_k order)

    #pragma unroll
    for (int e = 0; e < 4; ++e) {
        const int i = tid + 256*e;
        const float v = sv[i];
        const unsigned u = __float_as_uint(v);
        bool sel = (u > T);
        if (!sel && u == T) {
            int rank = 0;
            for (int j = 0; j < i; ++j) rank += (__float_as_uint(sv[j]) == T) ? 1 : 0;
            sel = (rank < m);
        }
        if (sel) {
            const unsigned p = atomicAdd(&sc[2], 1u);
            if (p < 104u) { sel_v[p] = v; sel_i[p] = i; }
        }
    }
    __syncthreads();

    rbuf[tid] = (tid < KTOP) ? sel_v[tid] : 0.f;
    __syncthreads();
    for (int st = 128; st > 0; st >>= 1) { if (tid < st) rbuf[tid] += rbuf[tid + st]; __syncthreads(); }
    const float sumtop = rbuf[0];
    __syncthreads();
    rbuf[tid] = (tid < KTOP) ? sel_v[tid] : -1.f;
    __syncthreads();
    for (int st = 128; st > 0; st >>= 1) { if (tid < st) rbuf[tid] = fmaxf(rbuf[tid], rbuf[tid + st]); __syncthreads(); }
    const float vmax = rbuf[0];
    __syncthreads();

    const float denom = sumtop + 1e-8f * srow_sh;  // == (sum tp + 1e-8) * S_row
    const float scl = (float)KTOP / denom;
    if (tid < KTOP) sel_w[tid] = expf(sel_v[tid] * scl - vmax * scl);
    __syncthreads();
    rbuf[tid] = (tid < KTOP) ? sel_w[tid] : 0.f;
    __syncthreads();
    for (int st = 128; st > 0; st >>= 1) { if (tid < st) rbuf[tid] += rbuf[tid + st]; __syncthreads(); }
    const float Z = rbuf[0];
    __syncthreads();

    if (tid < 128) {
        const int d = tid & 63;
        const int im = tid >> 6;
        const float* Vp = im ? Vim : Vre;
        const int base = h * 64 + d;
        float acc = 0.f;
        for (int j = 0; j < KTOP; ++j) acc += sel_w[j] * Vp[(size_t)sel_i[j] * 512 + base];
        acc /= Z;
        float* AOp = im ? AOim : AOre;
        AOp[(size_t)n * 512 + h * 64 + d] = acc;
    }
}

// ---------------------------------------------------------------------------
extern "C" void kernel_launch(void* const* d_in, const int* in_sizes, int n_in,
                              void* d_out, int out_size, void* d_ws, size_t ws_size,
                              hipStream_t stream)
{
    (void)in_sizes; (void)n_in; (void)d_ws; (void)ws_size;
    const float* x_re = (const float*)d_in[0];
    const float* x_im = (const float*)d_in[1];
    // d_in[10..13] (phase MLP) are dead code.

    float* pool = nullptr;
    hipGetSymbolAddress((void**)&pool, HIP_SYMBOL(g_pool));   // query only; capture-safe

    float* Wall = pool;                // 4 complex 512^2: [W0re|W0im|W1re|...]
    float* R    = Wall + 4*CMAT + 8192;   // union region (8192 pad legacy)
    // Phase A (all 4 weights batched): 6 buffers x 4 weights x CMAT
    float* A  = R;
    float* S  = R + 4*CMAT;
    float* S2 = R + 8*CMAT;
    float* X  = R + 12*CMAT;           // U, then NS ping
    float* X2 = R + 16*CMAT;           // X0, then NS pong
    float* T  = R + 20*CMAT;           // NS temp
    // Phase B (overlays the same region):
    float* Q  = R;                     // CPROJ floats each
    float* Kp = R + CPROJ;
    float* V  = R + 2*CPROJ;
    float* AO = R + 3*CPROJ;
    float* B2 = R + 4*CPROJ;           // 8 x 1024x1024

    const int aoff = (int)(A - pool);

    // ---- Phase A: Cayley unitaries, all 4 weights per dispatch ----
    build_A_kernel<<<dim3(16,16,4),256,0,stream>>>(
        (const float*)d_in[2],(const float*)d_in[3],(const float*)d_in[4],(const float*)d_in[5],
        (const float*)d_in[6],(const float*)d_in[7],(const float*)d_in[8],(const float*)d_in[9], aoff);
    // S = A*A   (mode 0)
    cgemm_kernel<<<dim3(8,16,4),256,0,stream>>>(A,A+PLANE,CMAT, A,A+PLANE,CMAT,
                                                A,A+PLANE,CMAT, A,nullptr,CMAT,
                                                S,S+PLANE,CMAT, 512,512,512, 0.f, 0, 0);
    // S2 = S*S; U = 5.5 S + 0.5 S2 -> X slot  (mode 2, D=S, Ewr=X)
    cgemm_kernel<<<dim3(8,16,4),256,0,stream>>>(S,S+PLANE,CMAT, S,S+PLANE,CMAT,
                                                S,S+PLANE,CMAT, S,X,CMAT,
                                                S2,S2+PLANE,CMAT, 512,512,512, 0.f, 2, 0);
    // X0 = (60.5 I + 48 S + 23 S2 + S2*U)/61.5 -> X2  (mode 3, D=S, E=S2)
    cgemm_kernel<<<dim3(8,16,4),256,0,stream>>>(S2,S2+PLANE,CMAT, X,X+PLANE,CMAT,
                                                S,S+PLANE,CMAT, S2,nullptr,CMAT,
                                                X2,X2+PLANE,CMAT, 512,512,512, 0.f, 3, 0);
    // 2 Newton-Schulz iterations: X <- X(2I - B X), B = I - S
    float* Xc = X2; float* Xn = X;     // X0 lives in X2; X slot (U) is dead
    for (int it = 0; it < 2; ++it) {
        // T = 1*X - S*X  (mode 1)
        cgemm_kernel<<<dim3(8,16,4),256,0,stream>>>(S,S+PLANE,CMAT, Xc,Xc+PLANE,CMAT,
                                                    Xc,Xc+PLANE,CMAT, S,nullptr,CMAT,
                                                    T,T+PLANE,CMAT, 512,512,512, 1.f, 1, 0);
        // Xn = 2*X - X*T  (mode 1)
        cgemm_kernel<<<dim3(8,16,4),256,0,stream>>>(Xc,Xc+PLANE,CMAT, T,T+PLANE,CMAT,
                                                    Xc,Xc+PLANE,CMAT, S,nullptr,CMAT,
                                                    Xn,Xn+PLANE,CMAT, 512,512,512, 2.f, 1, 0);
        float* tmp = Xc; Xc = Xn; Xn = tmp;
    }
    // W = 2X + 2*A*X - I  (mode 4, D=X) -> Wall   [= (I-A)^{-1}(I+A)]
    cgemm_kernel<<<dim3(8,16,4),256,0,stream>>>(A,A+PLANE,CMAT, Xc,Xc+PLANE,CMAT,
                                                Xc,Xc+PLANE,CMAT, S,nullptr,CMAT,
                                                Wall,Wall+PLANE,CMAT, 512,512,512, 0.f, 4, 0);

    // ---- Phase B: projections Q,K,V = x @ W[0..2] (batched z=3, mode 0) ----
    cgemm_kernel<<<dim3(8,32,3),256,0,stream>>>(x_re,x_im,0, Wall,Wall+PLANE,CMAT,
                                                x_re,x_im,0, S,nullptr,0,
                                                Q,Q+PPLANE,CPROJ, 1024,512,512, 0.f, 0, 0);

    scores_kernel<<<dim3(16,16,8),256,0,stream>>>(Q,Q+PPLANE, Kp,Kp+PPLANE, B2);
    select_kernel<<<8192,256,0,stream>>>(B2, V,V+PPLANE, AO,AO+PPLANE);

    // ---- Output projection straight to d_out (mode 5: bounded scalar) ----
    // z=2 row-halves via sA=sC=PLANE (row stride 512 floats); im plane
    // offset PPLANE is uniform; bnd = out_floats - b*PLANE inside.
    cgemm_kernel<<<dim3(8,16,2),256,0,stream>>>(AO,AO+PPLANE,PLANE, Wall+3*CMAT,Wall+3*CMAT+PLANE,0,
                                                AO,AO+PPLANE,0, S,nullptr,0,
                                                (float*)d_out,nullptr,PLANE, 512,512,512, 0.f, 5, out_size);
}